// Round 4
// baseline (164.451 us; speedup 1.0000x reference)
//
#include <hip/hip_runtime.h>

#define NH 6
#define HEAD_DIM 32
#define CCH 192
#define HH 56
#define WW 56
#define HWSZ (HH * WW)            // 3136
#define KPOS 9
#define SCALE 0.17677669529663687f  // 32^-0.5

// One pixel per 8-lane group; lane handles dims 4l..4l+3.
// QK^T: per-lane dot4 + xor-butterfly over 8 lanes -> all lanes hold logit.
// Softmax: redundant per lane (9-wide, trivial).
// PV: per-lane 4-dim accumulation, float4 store (wave store = 8 px * 128 B).
// No LDS, no barriers; 18816 waves of supply; all k/v loads independent.
__global__ __launch_bounds__(256, 4) void dilate_attn_v4(
    const float* __restrict__ q,
    const float* __restrict__ k,
    const float* __restrict__ v,
    float* __restrict__ out)
{
    const int tid = blockIdx.x * 256 + threadIdx.x;
    const int l   = tid & 7;        // d-quad id: dims 4l..4l+3
    const int p   = tid >> 3;       // pixel id 0..150527
    const int x   = p % WW;
    const int y   = (p / WW) % HH;
    const int bh  = p / HWSZ;       // b*NH + h

    const size_t dbase = ((size_t)bh * HEAD_DIM + 4 * l) * HWSZ;

    // q[4l..4l+3] for this pixel (4 coalesced-by-segment scalar loads)
    const float* qb = q + dbase + y * WW + x;
    const float q0 = qb[0];
    const float q1 = qb[HWSZ];
    const float q2 = qb[2 * HWSZ];
    const float q3 = qb[3 * HWSZ];

    const float* kb = k + dbase;
    const float* vb = v + dbase;

    // 9 taps: clamped offsets + masks (OOB -> logit 0, weight 0; matches zero-pad)
    int   off[KPOS];
    float msk[KPOS];
#pragma unroll
    for (int kk = 0; kk < KPOS; kk++) {
        const int yy = y + 2 * (kk / 3) - 2;
        const int xx = x + 2 * (kk % 3) - 2;
        const bool ok = (yy >= 0) & (yy < HH) & (xx >= 0) & (xx < WW);
        off[kk] = ok ? (yy * WW + xx) : (y * WW + x);   // clamp to center (valid)
        msk[kk] = ok ? 1.0f : 0.0f;
    }

    // ---- QK^T: partial dot over this lane's 4 dims, butterfly over 8 lanes ----
    float lg[KPOS];
#pragma unroll
    for (int kk = 0; kk < KPOS; kk++) {
        const float* kp = kb + off[kk];
        float pa =        q0 * kp[0];
        pa = fmaf(q1, kp[HWSZ],     pa);
        pa = fmaf(q2, kp[2 * HWSZ], pa);
        pa = fmaf(q3, kp[3 * HWSZ], pa);
        pa += __shfl_xor(pa, 1);
        pa += __shfl_xor(pa, 2);
        pa += __shfl_xor(pa, 4);
        lg[kk] = pa * SCALE * msk[kk];
    }

    // ---- softmax over the 9 taps (every lane redundantly) ----
    float m = lg[0];
#pragma unroll
    for (int kk = 1; kk < KPOS; kk++) m = fmaxf(m, lg[kk]);
    float s = 0.0f;
    float w[KPOS];
#pragma unroll
    for (int kk = 0; kk < KPOS; kk++) {
        w[kk] = __expf(lg[kk] - m);
        s += w[kk];
    }
    const float inv = 1.0f / s;
#pragma unroll
    for (int kk = 0; kk < KPOS; kk++) w[kk] *= inv * msk[kk];  // OOB v contributes 0

    // ---- PV over this lane's 4 dims ----
    float a0 = 0.f, a1 = 0.f, a2 = 0.f, a3 = 0.f;
#pragma unroll
    for (int kk = 0; kk < KPOS; kk++) {
        const float* vp = vb + off[kk];
        const float wk = w[kk];
        a0 = fmaf(wk, vp[0],         a0);
        a1 = fmaf(wk, vp[HWSZ],      a1);
        a2 = fmaf(wk, vp[2 * HWSZ],  a2);
        a3 = fmaf(wk, vp[3 * HWSZ],  a3);
    }

    // ---- store: out[b, y, x, h*32 + 4l .. +3] ----
    const int h = bh % NH;
    const int b = bh / NH;
    float* ob = out + ((size_t)((b * HH + y) * WW + x)) * CCH
                    + h * HEAD_DIM + 4 * l;
    *reinterpret_cast<float4*>(ob) = make_float4(a0, a1, a2, a3);
}

extern "C" void kernel_launch(void* const* d_in, const int* in_sizes, int n_in,
                              void* d_out, int out_size, void* d_ws, size_t ws_size,
                              hipStream_t stream) {
    const float* q = (const float*)d_in[0];
    const float* k = (const float*)d_in[1];
    const float* v = (const float*)d_in[2];
    float* out = (float*)d_out;

    // 150528 pixels * 8 lanes = 1204224 threads = 4704 blocks of 256
    const int blocks = (8 * NH * HWSZ * 8) / 256;
    dilate_attn_v4<<<blocks, 256, 0, stream>>>(q, k, v, out);
}

// Round 5
// 108.189 us; speedup vs baseline: 1.5200x; 1.5200x over previous
//
#include <hip/hip_runtime.h>

#define NH 6
#define HEAD_DIM 32
#define CCH 192
#define HH 56
#define WW 56
#define HWSZ (HH * WW)            // 3136
#define KPOS 9
#define SCALE 0.17677669529663687f  // 32^-0.5
#define XPAD 61                   // LDS x-stride: 60 used + 1 -> 2-way max conflicts (free)
#define ROWSZ (HEAD_DIM * XPAD)   // 1952 floats per (row) plane

// Block = (bh, y). Stage k/v rows y-2, y, y+2 into LDS with zero padding baked
// in (x' = x+2, pad cols 0,1,58,59 zero; OOB rows fully zero). Compute phase:
// thread = (px, c) with c = dim-octet (8 dims); all 9 taps read from LDS at
// x' = px + 2*ix -- branch-free, matches reference zero-pad semantics exactly.
__global__ __launch_bounds__(256, 3) void dilate_attn_lds(
    const float* __restrict__ q,
    const float* __restrict__ k,
    const float* __restrict__ v,
    float* __restrict__ out)
{
    __shared__ float ks[3 * ROWSZ];
    __shared__ float vs[3 * ROWSZ];

    // bh-inner ordering: (bh, y) and (bh, y+1) are 48 block-ids apart ->
    // same XCD (48 % 8 == 0) -> row overlap served by that XCD's L2.
    const int bh = blockIdx.x % 48;
    const int y  = blockIdx.x / 48;
    const int t  = threadIdx.x;

    const int px = t >> 2;        // 0..63 (valid < 56)
    const int c  = t & 3;         // dim-octet: dims 8c..8c+7
    const bool active = px < WW;

    // ---- q prefetch (independent of LDS; issue before staging) ----
    float qreg[8];
    if (active) {
        const float* qb = q + ((size_t)bh * HEAD_DIM + 8 * c) * HWSZ + y * WW + px;
#pragma unroll
        for (int j = 0; j < 8; j++) qreg[j] = qb[j * HWSZ];
    }

    // ---- stage k/v rows into LDS (zero-padded) ----
    const size_t plane = (size_t)bh * HEAD_DIM * HWSZ;
#pragma unroll
    for (int r = 0; r < 3; r++) {
        const int sy = y + 2 * r - 2;
        float* kd = ks + r * ROWSZ;
        float* vd = vs + r * ROWSZ;
        if (sy >= 0 && sy < HH) {
            const float* kg = k + plane + sy * WW;
            const float* vg = v + plane + sy * WW;
#pragma unroll
            for (int i = 0; i < 7; i++) {              // 7*256 = 1792 = 32*56
                const int idx = t + 256 * i;
                const int d = idx / WW;
                const int x = idx - d * WW;
                const float kvv = kg[d * HWSZ + x];
                const float vvv = vg[d * HWSZ + x];
                kd[d * XPAD + x + 2] = kvv;
                vd[d * XPAD + x + 2] = vvv;
            }
            // zero pad columns x' in {0,1,58,59}: 32 d * 4 cols = 128 elems/tensor
            if (t < 128) {
                const int d  = t >> 2;
                const int xc = t & 3;
                const int xp = (xc < 2) ? xc : (56 + xc);   // 0,1,58,59
                kd[d * XPAD + xp] = 0.0f;
                vd[d * XPAD + xp] = 0.0f;
            }
        } else {
            // OOB row: zero the whole plane (1952 floats per tensor)
#pragma unroll
            for (int i = 0; i < 8; i++) {
                const int idx = t + 256 * i;
                if (idx < ROWSZ) { kd[idx] = 0.0f; vd[idx] = 0.0f; }
            }
        }
    }
    __syncthreads();

    if (!active) return;   // no further barriers

    // ---- QK^T from LDS: taps (r, ix) at x' = px + 2*ix ----
    float lg[KPOS];
#pragma unroll
    for (int r = 0; r < 3; r++) {
        const float* kr = ks + r * ROWSZ + (8 * c) * XPAD + px;
        float a0 = 0.f, a1 = 0.f, a2 = 0.f;
#pragma unroll
        for (int j = 0; j < 8; j++) {
            const float* p = kr + j * XPAD;
            const float qj = qreg[j];
            a0 = fmaf(qj, p[0], a0);
            a1 = fmaf(qj, p[2], a1);
            a2 = fmaf(qj, p[4], a2);
        }
        lg[3 * r + 0] = a0;
        lg[3 * r + 1] = a1;
        lg[3 * r + 2] = a2;
    }

    // ---- reduce partial dots over the 4 c-lanes (lanes 4px..4px+3) ----
#pragma unroll
    for (int kk = 0; kk < KPOS; kk++) {
        float s = lg[kk];
        s += __shfl_xor(s, 1);
        s += __shfl_xor(s, 2);
        lg[kk] = s * SCALE;
    }

    // ---- softmax over 9 taps (redundant per lane) ----
    float m = lg[0];
#pragma unroll
    for (int kk = 1; kk < KPOS; kk++) m = fmaxf(m, lg[kk]);
    float ssum = 0.f;
    float w[KPOS];
#pragma unroll
    for (int kk = 0; kk < KPOS; kk++) {
        w[kk] = __expf(lg[kk] - m);
        ssum += w[kk];
    }
    const float inv = 1.f / ssum;
#pragma unroll
    for (int kk = 0; kk < KPOS; kk++) w[kk] *= inv;

    // ---- PV from LDS ----
    float acc[8];
#pragma unroll
    for (int j = 0; j < 8; j++) acc[j] = 0.f;
#pragma unroll
    for (int r = 0; r < 3; r++) {
        const float* vr = vs + r * ROWSZ + (8 * c) * XPAD + px;
        const float w0 = w[3 * r + 0];
        const float w1 = w[3 * r + 1];
        const float w2 = w[3 * r + 2];
#pragma unroll
        for (int j = 0; j < 8; j++) {
            const float* p = vr + j * XPAD;
            float a = acc[j];
            a = fmaf(w0, p[0], a);
            a = fmaf(w1, p[2], a);
            a = fmaf(w2, p[4], a);
            acc[j] = a;
        }
    }

    // ---- store: out[b, y, px, h*32 + 8c .. +7] ----
    const int h = bh % NH;
    const int b = bh / NH;
    float* ob = out + ((size_t)((b * HH + y) * WW + px)) * CCH
                    + h * HEAD_DIM + 8 * c;
    reinterpret_cast<float4*>(ob)[0] = make_float4(acc[0], acc[1], acc[2], acc[3]);
    reinterpret_cast<float4*>(ob)[1] = make_float4(acc[4], acc[5], acc[6], acc[7]);
}

extern "C" void kernel_launch(void* const* d_in, const int* in_sizes, int n_in,
                              void* d_out, int out_size, void* d_ws, size_t ws_size,
                              hipStream_t stream) {
    const float* q = (const float*)d_in[0];
    const float* k = (const float*)d_in[1];
    const float* v = (const float*)d_in[2];
    float* out = (float*)d_out;

    const int blocks = 48 * HH;   // (bh inner, y outer) = 2688
    dilate_attn_lds<<<blocks, 256, 0, stream>>>(q, k, v, out);
}